// Round 7
// baseline (1061.325 us; speedup 1.0000x reference)
//
#include <hip/hip_runtime.h>
#include <hip/hip_bf16.h>

typedef __attribute__((ext_vector_type(8))) short short8v;
typedef __attribute__((ext_vector_type(4))) float f32x4;
typedef unsigned short ushort_t;

#define NANG 1000000
#define NBOND 500000
#define NATOM 100000
#define BM 64

static __device__ __forceinline__ ushort_t f2bf(float f) {
    union { float f; unsigned u; } v; v.f = f;
    unsigned r = v.u + 0x7FFFu + ((v.u >> 16) & 1u);
    return (ushort_t)(r >> 16);
}
static __device__ __forceinline__ int load_idx(const void* p, long long i, bool is64) {
    return is64 ? (int)((const long long*)p)[i] : ((const int*)p)[i];
}

// ---- detect index width: int64 small values look valid; int32 data read as
// int64 combines pairs -> huge values -> detected as int32. ----
__global__ void detect_idx_kernel(const void* edge_src, int* flag) {
    const long long* p = (const long long*)edge_src;
    long long v = p[threadIdx.x & 63];
    int bad = (v < 0 || v >= NBOND) ? 1 : 0;
    unsigned long long m = __ballot(bad);
    if (threadIdx.x == 0) *flag = (m == 0ull) ? 1 : 0;
}

// ---- repack fp32 weights into bf16 B-fragment order ----
// Wpack1: [kt(8)][g(4)][n(256)][j(8)] ; elem = W1cat[k=kt*32+g*8+j][n]
//   W1cat col n<128 -> gW1[k][n] (gate hidden), else oW1[k][n-128] (out hidden)
// Wpack2g/o at +65536/+73728: [kt(4)][g(4)][n(64)][j(8)] ; elem = W2[k][n]
__global__ void prep_weights_kernel(const float* __restrict__ gW1,
                                    const float* __restrict__ gW2,
                                    const float* __restrict__ oW1,
                                    const float* __restrict__ oW2,
                                    ushort_t* __restrict__ wpack) {
    int e = blockIdx.x * 256 + threadIdx.x;
    if (e < 65536) {
        int j = e & 7, n = (e >> 3) & 255, g = (e >> 11) & 3, kt = e >> 13;
        int k = kt * 32 + g * 8 + j;
        wpack[e] = f2bf((n < 128) ? gW1[k * 128 + n] : oW1[k * 128 + (n - 128)]);
    } else if (e < 73728) {
        int e2 = e - 65536;
        int j = e2 & 7, n = (e2 >> 3) & 63, g = (e2 >> 9) & 3, kt = e2 >> 11;
        wpack[e] = f2bf(gW2[(kt * 32 + g * 8 + j) * 64 + n]);
    } else if (e < 81920) {
        int e2 = e - 73728;
        int j = e2 & 7, n = (e2 >> 3) & 63, g = (e2 >> 9) & 3, kt = e2 >> 11;
        wpack[e] = f2bf(oW2[(kt * 32 + g * 8 + j) * 64 + n]);
    }
}

__launch_bounds__(256, 3)
__global__ void angle_update_kernel(
    const float* __restrict__ atom_feat,
    const float* __restrict__ bond_feat,
    const float* __restrict__ angle_feat,
    const void*  __restrict__ angle_index,
    const void*  __restrict__ edge_src,
    const void*  __restrict__ edge_dst,
    const float* __restrict__ gb1,
    const float* __restrict__ gb2,
    const float* __restrict__ ob1,
    const float* __restrict__ ob2,
    const ushort_t* __restrict__ wpack,
    const int*   __restrict__ flag64,
    float*       __restrict__ out)
{
    // xh: x tile (64 x 256 bf16, XOR-swizzled) -> reused for h -> reused (as
    // float [64][68]) for the result tile before coalesced copy-out
    __shared__ __align__(16) ushort_t xh[BM * 256];
    __shared__ __align__(16) ushort_t wl[8192];      // 16 KB W k-step tile

    const int tid = threadIdx.x;
    const int lane = tid & 63;
    const int wid = tid >> 6;
    const int l15 = lane & 15;
    const int kg = lane >> 4;
    const int ablock = blockIdx.x * BM;
    const bool is64 = (*flag64 != 0);

    // ---- stage x tile: 64 rows x 32 chunks(8 bf16); read fp32, cvt bf16 ----
    // x layout per row: [src_bond(64) | dst_bond(64) | angle(64) | vertex(64)]
    for (int it = 0; it < 8; ++it) {
        int task = it * 256 + tid;          // 0..2047
        int row = task >> 5;
        int chunk = task & 31;
        int a = ablock + row;
        int off = (chunk & 7) * 8;          // float offset within feature
        const float* src;
        if (chunk < 8) {
            src = bond_feat + (size_t)load_idx(edge_src, a, is64) * 64 + off;
        } else if (chunk < 16) {
            src = bond_feat + (size_t)load_idx(edge_dst, a, is64) * 64 + off;
        } else if (chunk < 24) {
            src = angle_feat + (size_t)a * 64 + off;
        } else {
            src = atom_feat + (size_t)load_idx(angle_index, (long long)a * 3 + 1, is64) * 64 + off;
        }
        float4 fa = *(const float4*)src;
        float4 fb = *(const float4*)(src + 4);
        short8v v;
        v[0] = (short)f2bf(fa.x); v[1] = (short)f2bf(fa.y);
        v[2] = (short)f2bf(fa.z); v[3] = (short)f2bf(fa.w);
        v[4] = (short)f2bf(fb.x); v[5] = (short)f2bf(fb.y);
        v[6] = (short)f2bf(fb.z); v[7] = (short)f2bf(fb.w);
        int byte = (row * 512 + chunk * 16) ^ ((row & 7) << 4);
        *(short8v*)((char*)xh + byte) = v;
    }
    __syncthreads();

    // ---- GEMM1: h_pre[64][256] = x[64][256] @ W1cat[256][256] ----
    f32x4 acc[16];
    #pragma unroll
    for (int i = 0; i < 16; ++i) acc[i] = (f32x4){0.f, 0.f, 0.f, 0.f};

    const int wrow = wid * 16;
    const int arow = wrow + l15;

    for (int kt = 0; kt < 8; ++kt) {
        {   // stage 16 KB W1 k-step tile
            const short8v* s = (const short8v*)(wpack + kt * 8192);
            short8v* d = (short8v*)wl;
            #pragma unroll
            for (int i = 0; i < 4; ++i) d[tid + i * 256] = s[tid + i * 256];
        }
        __syncthreads();
        int abyte = (arow * 512 + (kt * 32 + kg * 8) * 2) ^ ((arow & 7) << 4);
        short8v afrag = *(const short8v*)((const char*)xh + abyte);
        #pragma unroll
        for (int n0 = 0; n0 < 16; ++n0) {
            short8v bfrag = *(const short8v*)((const char*)wl + kg * 4096 + (n0 * 16 + l15) * 16);
            acc[n0] = __builtin_amdgcn_mfma_f32_16x16x32_bf16(afrag, bfrag, acc[n0], 0, 0, 0);
        }
        __syncthreads();
    }

    // ---- h = relu(acc + b1) -> bf16, swizzled, into xh (x fully consumed) ----
    #pragma unroll
    for (int t = 0; t < 16; ++t) {
        int col = t * 16 + l15;
        float b = (col < 128) ? gb1[col] : ob1[col - 128];
        #pragma unroll
        for (int r = 0; r < 4; ++r) {
            int row = wrow + kg * 4 + r;
            float v = fmaxf(acc[t][r] + b, 0.f);
            int byte = (row * 512 + col * 2) ^ ((row & 7) << 4);
            *(ushort_t*)((char*)xh + byte) = f2bf(v);
        }
    }
    __syncthreads();

    // ---- GEMM2: gate_pre = h[:,0:128] @ gW2 ; out_pre = h[:,128:256] @ oW2 ----
    f32x4 accg[4], acco[4];
    #pragma unroll
    for (int i = 0; i < 4; ++i) { accg[i] = (f32x4){0.f,0.f,0.f,0.f}; acco[i] = (f32x4){0.f,0.f,0.f,0.f}; }

    for (int kt = 0; kt < 4; ++kt) {
        {   // stage 4 KB gate tile + 4 KB out tile
            const short8v* sg = (const short8v*)(wpack + 65536 + kt * 2048);
            const short8v* so = (const short8v*)(wpack + 73728 + kt * 2048);
            short8v* d = (short8v*)wl;
            d[tid]       = sg[tid];
            d[256 + tid] = so[tid];
        }
        __syncthreads();
        int kc = (kt * 32 + kg * 8) * 2;
        int bgb = (arow * 512 + kc)       ^ ((arow & 7) << 4);
        int bob = (arow * 512 + 256 + kc) ^ ((arow & 7) << 4);
        short8v ag = *(const short8v*)((const char*)xh + bgb);
        short8v ao = *(const short8v*)((const char*)xh + bob);
        #pragma unroll
        for (int n0 = 0; n0 < 4; ++n0) {
            short8v bg = *(const short8v*)((const char*)wl + kg * 1024 + (n0 * 16 + l15) * 16);
            short8v bo = *(const short8v*)((const char*)wl + 4096 + kg * 1024 + (n0 * 16 + l15) * 16);
            accg[n0] = __builtin_amdgcn_mfma_f32_16x16x32_bf16(ag, bg, accg[n0], 0, 0, 0);
            acco[n0] = __builtin_amdgcn_mfma_f32_16x16x32_bf16(ao, bo, acco[n0], 0, 0, 0);
        }
        __syncthreads();
    }

    // ---- epilogue: res = angle_feat + silu(out_pre) * sigmoid(gate_pre) ----
    // write fp32 into LDS [64][68] (reuse xh; 68 floats = 272B, 16B-aligned)
    float* resl = (float*)xh;
    #pragma unroll
    for (int t = 0; t < 4; ++t) {
        int col = t * 16 + l15;
        float b_g = gb2[col];
        float b_o = ob2[col];
        #pragma unroll
        for (int r = 0; r < 4; ++r) {
            int row = wrow + kg * 4 + r;
            float gp = accg[t][r] + b_g;
            float op = acco[t][r] + b_o;
            float gate = 1.f / (1.f + __expf(-gp));
            float so = op / (1.f + __expf(-op));
            resl[row * 68 + col] = angle_feat[(size_t)(ablock + row) * 64 + col] + so * gate;
        }
    }
    __syncthreads();

    {   // coalesced float4 stores: 1024 chunks, 4 per thread
        float* outp = out + (size_t)ablock * 64;
        #pragma unroll
        for (int i = 0; i < 4; ++i) {
            int c = i * 256 + tid;          // 0..1023
            int row = c >> 4;
            int cc = c & 15;
            *(float4*)(outp + c * 4) = *(const float4*)(resl + row * 68 + cc * 4);
        }
    }
}

extern "C" void kernel_launch(void* const* d_in, const int* in_sizes, int n_in,
                              void* d_out, int out_size, void* d_ws, size_t ws_size,
                              hipStream_t stream) {
    const float* atom_feat  = (const float*)d_in[0];
    const float* bond_feat  = (const float*)d_in[1];
    const float* angle_feat = (const float*)d_in[2];
    const void*  angle_index = d_in[3];
    const void*  edge_src    = d_in[4];
    const void*  edge_dst    = d_in[5];
    const float* gW1 = (const float*)d_in[6];
    const float* gb1 = (const float*)d_in[7];
    const float* gW2 = (const float*)d_in[8];
    const float* gb2 = (const float*)d_in[9];
    const float* oW1 = (const float*)d_in[10];
    const float* ob1 = (const float*)d_in[11];
    const float* oW2 = (const float*)d_in[12];
    const float* ob2 = (const float*)d_in[13];

    ushort_t* wpack = (ushort_t*)d_ws;                    // 81920 bf16 = 160 KB
    int* flag64 = (int*)((char*)d_ws + 163840);

    detect_idx_kernel<<<1, 64, 0, stream>>>(edge_src, flag64);
    prep_weights_kernel<<<320, 256, 0, stream>>>(gW1, gW2, oW1, oW2, wpack);
    angle_update_kernel<<<NANG / BM, 256, 0, stream>>>(
        atom_feat, bond_feat, angle_feat, angle_index, edge_src, edge_dst,
        gb1, gb2, ob1, ob2, wpack, flag64, (float*)d_out);
}